// Round 1
// baseline (106.225 us; speedup 1.0000x reference)
//
#include <hip/hip_runtime.h>
#include <math.h>

#define NN   8
#define INCH 32
#define INN  50000
#define OUTC 64
#define OUTN 8192
#define DD   32
#define CC   256   // NN*INCH

// Kernel 1: yT[j][c] = x[c][j] * nf[c%32][j], with c = n*32+i (x is (n,i,j) so row c = flat n*32+i)
__global__ __launch_bounds__(256) void prep_kernel(
    const float* __restrict__ x, const float* __restrict__ nf, float* __restrict__ yT) {
  __shared__ float tile[CC][33];   // pad 33: stride-33 accesses are bank-conflict-free
  const int t = threadIdx.x;
  const int j0 = blockIdx.x * 32;
  const int jmax = min(32, INN - j0);

  // load: thread t owns row c=t; reads 32 consecutive j as float4 (aligned: 50000%4==0, j0%4==0)
  {
    const float* xr = x + (size_t)t * INN + j0;
    const float* nr = nf + (size_t)(t & 31) * INN + j0;
    #pragma unroll
    for (int jj = 0; jj < 8; ++jj) {
      if (jj * 4 < jmax) {
        const float4 xv = *(const float4*)(xr + jj * 4);
        const float4 nv = *(const float4*)(nr + jj * 4);
        tile[t][jj * 4 + 0] = xv.x * nv.x;
        tile[t][jj * 4 + 1] = xv.y * nv.y;
        tile[t][jj * 4 + 2] = xv.z * nv.z;
        tile[t][jj * 4 + 3] = xv.w * nv.w;
      }
    }
  }
  __syncthreads();

  // store transposed: wave-contiguous 256B stores along c
  const int cl = t & 63;
  const int wq = t >> 6;
  #pragma unroll
  for (int rr = 0; rr < 8; ++rr) {
    const int jl = wq + 4 * rr;
    if (jl < jmax) {
      float* dst = yT + (size_t)(j0 + jl) * CC;
      #pragma unroll
      for (int cc = 0; cc < 4; ++cc) {
        const int cw = cl + 64 * cc;
        dst[cw] = tile[cw][jl];   // read stride 33 -> conflict-free
      }
    }
  }
}

// Kernel 2: per block of 32 o's: gather+max into LDS, then red @ ft + bias
__global__ __launch_bounds__(256) void gmm_kernel(
    const float* __restrict__ yT, const float* __restrict__ ft,
    const float* __restrict__ bias, const int* __restrict__ A,
    float* __restrict__ out) {
  __shared__ __align__(16) float red[32][CC];   // [o_local][c], rows 1KB -> float4-aligned
  __shared__ float obuf[64][33];                // [k][o_local] transpose bounce
  const int t = threadIdx.x;
  const int lane = t & 63;
  const int wave = t >> 6;
  const int o0 = blockIdx.x * 32;

  // lane = k: ft column in registers (coalesced global read, L2-resident)
  float ftreg[32];
  #pragma unroll
  for (int i = 0; i < 32; ++i) ftreg[i] = ft[i * OUTC + lane];

  // bias for the write-out mapping (o on lane axis -> coalesced)
  const int oc = t & 31, kb = t >> 5;
  float br[8];
  #pragma unroll
  for (int r = 0; r < 8; ++r)
    br[r] = bias[(size_t)(kb * 8 + r) * OUTN + o0 + oc];

  // ---- Phase A: gather + max. Wave owns o; each index -> one contiguous 1KB read.
  for (int oo = wave; oo < 32; oo += 4) {
    const int* Ao = A + (size_t)(o0 + oo) * DD;
    float4 acc = make_float4(-INFINITY, -INFINITY, -INFINITY, -INFINITY);
    #pragma unroll
    for (int d = 0; d < DD; ++d) {
      const int idx = Ao[d];                    // wave-uniform -> scalar load
      const float4 v = *((const float4*)(yT + (size_t)idx * CC) + lane);
      acc.x = fmaxf(acc.x, v.x);
      acc.y = fmaxf(acc.y, v.y);
      acc.z = fmaxf(acc.z, v.z);
      acc.w = fmaxf(acc.w, v.w);
    }
    *((float4*)(&red[oo][0]) + lane) = acc;     // contiguous 1KB wave write, conflict-free
  }
  __syncthreads();

  // ---- Phase B/C: out[n,k,o] = sum_i red[o][n*32+i]*ft[i][k] + bias[k][o]
  for (int n = 0; n < 8; ++n) {
    #pragma unroll
    for (int jj = 0; jj < 8; ++jj) {
      const int o = (wave << 3) + jj;
      const float* rp = &red[o][n * 32];
      float acc = 0.f;
      #pragma unroll
      for (int q = 0; q < 8; ++q) {
        const float4 rv = *((const float4*)rp + q);   // uniform addr -> LDS broadcast
        acc += rv.x * ftreg[4 * q + 0] + rv.y * ftreg[4 * q + 1]
             + rv.z * ftreg[4 * q + 2] + rv.w * ftreg[4 * q + 3];
      }
      obuf[lane][o] = acc;                            // stride 33 -> conflict-free
    }
    __syncthreads();
    {
      float* op = out + (size_t)n * OUTC * OUTN + o0 + oc;
      #pragma unroll
      for (int r = 0; r < 8; ++r) {
        const int k = kb * 8 + r;
        op[(size_t)k * OUTN] = obuf[k][oc] + br[r];   // 128B-contiguous stores
      }
    }
    __syncthreads();
  }
}

extern "C" void kernel_launch(void* const* d_in, const int* in_sizes, int n_in,
                              void* d_out, int out_size, void* d_ws, size_t ws_size,
                              hipStream_t stream) {
  const float* x    = (const float*)d_in[0];
  const float* nf   = (const float*)d_in[1];
  const float* ft   = (const float*)d_in[2];
  const float* bias = (const float*)d_in[3];
  const int*   A    = (const int*)d_in[4];
  float* out = (float*)d_out;
  float* yT  = (float*)d_ws;   // needs 50000*256*4 = 51.2 MB

  hipLaunchKernelGGL(prep_kernel, dim3((INN + 31) / 32), dim3(256), 0, stream, x, nf, yT);
  hipLaunchKernelGGL(gmm_kernel, dim3(OUTN / 32), dim3(256), 0, stream, yT, ft, bias, A, out);
}

// Round 2
// 68.138 us; speedup vs baseline: 1.5590x; 1.5590x over previous
//
#include <hip/hip_runtime.h>
#include <math.h>

#define NN   8
#define INCH 32
#define INN  50000
#define OUTC 64
#define OUTN 8192
#define DD   32
#define CC   256   // NN*INCH

typedef unsigned short ushortT;

__device__ __forceinline__ ushortT f2bf(float f) {
  unsigned u = __float_as_uint(f);
  unsigned r = (u + 0x7FFFu + ((u >> 16) & 1u)) >> 16;   // round-nearest-even
  return (ushortT)r;
}
__device__ __forceinline__ float bf2f(ushortT b) {
  return __uint_as_float(((unsigned)b) << 16);
}

// Kernel 1: yT[j][p] bf16, permuted layout: ushort position p = 4*l + m  <->  c = 64*m + l
__global__ __launch_bounds__(256) void prep_kernel(
    const float* __restrict__ x, const float* __restrict__ nf, ushortT* __restrict__ yT) {
  __shared__ float tile[CC][33];   // stride 33 words: conflict-free both phases
  const int t = threadIdx.x;
  const int j0 = blockIdx.x * 32;
  const int jmax = min(32, INN - j0);

  // load: thread t owns row c=t; 32 consecutive j as float4
  {
    const float* xr = x + (size_t)t * INN + j0;
    const float* nr = nf + (size_t)(t & 31) * INN + j0;
    #pragma unroll
    for (int jj = 0; jj < 8; ++jj) {
      if (jj * 4 < jmax) {
        const float4 xv = *(const float4*)(xr + jj * 4);
        const float4 nv = *(const float4*)(nr + jj * 4);
        tile[t][jj * 4 + 0] = xv.x * nv.x;
        tile[t][jj * 4 + 1] = xv.y * nv.y;
        tile[t][jj * 4 + 2] = xv.z * nv.z;
        tile[t][jj * 4 + 3] = xv.w * nv.w;
      }
    }
  }
  __syncthreads();

  // store: one full 512B yT row per wave-instruction (ushort4/lane), permuted pack
  const int lane = t & 63;
  const int wave = t >> 6;
  #pragma unroll
  for (int r = 0; r < 8; ++r) {
    const int jl = wave * 8 + r;
    if (jl < jmax) {
      ushort4 pk;
      pk.x = f2bf(tile[lane][jl]);          // bank (lane+jl)%32 -> 2-way max (free)
      pk.y = f2bf(tile[64 + lane][jl]);
      pk.z = f2bf(tile[128 + lane][jl]);
      pk.w = f2bf(tile[192 + lane][jl]);
      ((ushort4*)(yT + (size_t)(j0 + jl) * CC))[lane] = pk;
    }
  }
}

// Kernel 2: one wave per o: gather+max over 32 indices, write red[o][c] (f32)
__global__ __launch_bounds__(256) void gather_kernel(
    const ushortT* __restrict__ yT, const int* __restrict__ A, float* __restrict__ red) {
  const int t = threadIdx.x;
  const int lane = t & 63;
  const int wave = t >> 6;
  const int o = blockIdx.x * 4 + wave;

  const int4* A4 = (const int4*)(A + (size_t)o * DD);
  int4 id[8];
  #pragma unroll
  for (int q = 0; q < 8; ++q) id[q] = A4[q];

  float a0 = -INFINITY, a1 = -INFINITY, a2 = -INFINITY, a3 = -INFINITY;
  #pragma unroll
  for (int q = 0; q < 8; ++q) {
    int ids[4] = {id[q].x, id[q].y, id[q].z, id[q].w};
    #pragma unroll
    for (int e = 0; e < 4; ++e) {
      const ushort4 v = ((const ushort4*)(yT + (size_t)ids[e] * CC))[lane];
      a0 = fmaxf(a0, bf2f(v.x));
      a1 = fmaxf(a1, bf2f(v.y));
      a2 = fmaxf(a2, bf2f(v.z));
      a3 = fmaxf(a3, bf2f(v.w));
    }
  }
  // un-permute: ushort slot 4*lane+m held c = 64*m+lane -> 4 coalesced 256B stores
  float* ro = red + (size_t)o * CC + lane;
  ro[0]   = a0;
  ro[64]  = a1;
  ro[128] = a2;
  ro[192] = a3;
}

// Kernel 3: out[n,k,o] = sum_i red[o][n*32+i]*ft[i][k] + bias[k][o]
// block: n-pair (np) x 64-o tile; wave: (n parity, k-half); lane = o_local
__global__ __launch_bounds__(256) void out_kernel(
    const float* __restrict__ red, const float* __restrict__ ft,
    const float* __restrict__ bias, float* __restrict__ out) {
  __shared__ float rtile[64][65];   // [o_local][c_local], pad 65 -> 2-way max on reads
  __shared__ float ftl[32][64];
  const int t = threadIdx.x;
  const int lane = t & 63;
  const int wave = t >> 6;
  const int np = blockIdx.x >> 7;   // 0..3
  const int ot = blockIdx.x & 127;  // 0..127
  const int o0 = ot * 64;
  const int c0 = np * 64;

  // ft -> LDS (2048 floats, coalesced)
  #pragma unroll
  for (int q = 0; q < 8; ++q) {
    const int idx = q * 256 + t;
    ftl[idx >> 6][idx & 63] = ft[idx];
  }
  // red tile -> LDS: per pass a wave loads 4 rows x 256B contiguous
  #pragma unroll
  for (int rr = 0; rr < 4; ++rr) {
    const int row = wave * 16 + rr * 4 + (lane >> 4);
    const int cq = (lane & 15) * 4;
    const float4 v = *(const float4*)(red + (size_t)(o0 + row) * CC + c0 + cq);
    rtile[row][cq + 0] = v.x;
    rtile[row][cq + 1] = v.y;
    rtile[row][cq + 2] = v.z;
    rtile[row][cq + 3] = v.w;
  }
  __syncthreads();

  const int n  = np * 2 + (wave & 1);
  const int kh = (wave >> 1) * 32;
  const int cb = (wave & 1) * 32;

  float rv[32];
  #pragma unroll
  for (int i = 0; i < 32; ++i) rv[i] = rtile[lane][cb + i];   // (lane+cb+i)%32 -> 2-way

  float acc[32];
  #pragma unroll
  for (int kk = 0; kk < 32; ++kk) acc[kk] = 0.f;
  #pragma unroll
  for (int i = 0; i < 32; ++i) {
    #pragma unroll
    for (int kk = 0; kk < 32; ++kk)
      acc[kk] += rv[i] * ftl[i][kh + kk];   // ftl: uniform addr -> broadcast
  }

  float* op = out + (size_t)n * OUTC * OUTN + o0 + lane;
  const float* bp = bias + o0 + lane;
  #pragma unroll
  for (int kk = 0; kk < 32; ++kk) {
    const int k = kh + kk;
    op[(size_t)k * OUTN] = acc[kk] + bp[(size_t)k * OUTN];   // 256B-contiguous stores
  }
}

extern "C" void kernel_launch(void* const* d_in, const int* in_sizes, int n_in,
                              void* d_out, int out_size, void* d_ws, size_t ws_size,
                              hipStream_t stream) {
  const float* x    = (const float*)d_in[0];
  const float* nf   = (const float*)d_in[1];
  const float* ft   = (const float*)d_in[2];
  const float* bias = (const float*)d_in[3];
  const int*   A    = (const int*)d_in[4];
  float* out = (float*)d_out;

  ushortT* yT = (ushortT*)d_ws;                               // 50000*256*2 = 25.6 MB
  float*   red = (float*)((char*)d_ws + (size_t)INN * CC * 2); // 8192*256*4 = 8.4 MB

  hipLaunchKernelGGL(prep_kernel,   dim3((INN + 31) / 32), dim3(256), 0, stream, x, nf, yT);
  hipLaunchKernelGGL(gather_kernel, dim3(OUTN / 4),        dim3(256), 0, stream, yT, A, red);
  hipLaunchKernelGGL(out_kernel,    dim3(512),             dim3(256), 0, stream, red, ft, bias, out);
}

// Round 3
// 52.738 us; speedup vs baseline: 2.0142x; 1.2920x over previous
//
#include <hip/hip_runtime.h>
#include <math.h>

#define NN   8
#define INCH 32
#define INN  50000
#define OUTC 64
#define OUTN 8192
#define DD   32
#define CC   256   // NN*INCH

typedef unsigned short ushortT;

__device__ __forceinline__ ushortT f2bf(float f) {
  unsigned u = __float_as_uint(f);
  unsigned r = (u + 0x7FFFu + ((u >> 16) & 1u)) >> 16;   // round-nearest-even
  return (ushortT)r;
}
__device__ __forceinline__ float bf2f(ushortT b) {
  return __uint_as_float(((unsigned)b) << 16);
}

// Kernel 1: yT[j][p] bf16, permuted layout: ushort position p = 4*l + m  <->  c = 64*m + l
// Read mapping: 8 lanes per row (128B contiguous per lane-group) -> coalesced segments.
__global__ __launch_bounds__(256) void prep_kernel(
    const float* __restrict__ x, const float* __restrict__ nf, ushortT* __restrict__ yT) {
  __shared__ float tile[CC][33];   // stride 33 words: <=2-way banks both phases
  const int t = threadIdx.x;
  const int j0 = blockIdx.x * 32;
  const int jmax = min(32, INN - j0);   // 50000 = 1562*32 + 16 -> last block 16

  const int q  = t & 7;    // j-quad within window
  const int r0 = t >> 3;   // row within 32-row group

  if (q * 4 < jmax) {
    // nf row = c & 31 = r0 for every pass -> loop-invariant
    const float4 nv = *(const float4*)(nf + (size_t)r0 * INN + j0 + 4 * q);
    #pragma unroll
    for (int p = 0; p < 8; ++p) {
      const int c = (p << 5) + r0;
      const float4 xv = *(const float4*)(x + (size_t)c * INN + j0 + 4 * q);
      tile[c][4 * q + 0] = xv.x * nv.x;
      tile[c][4 * q + 1] = xv.y * nv.y;
      tile[c][4 * q + 2] = xv.z * nv.z;
      tile[c][4 * q + 3] = xv.w * nv.w;
    }
  }
  __syncthreads();

  // store: one full 512B yT row per wave-instruction (ushort4/lane), permuted pack
  const int lane = t & 63;
  const int wave = t >> 6;
  #pragma unroll
  for (int r = 0; r < 8; ++r) {
    const int jl = wave * 8 + r;
    if (jl < jmax) {
      ushort4 pk;
      pk.x = f2bf(tile[lane][jl]);          // bank (lane+jl)%32 -> 2-way max (free)
      pk.y = f2bf(tile[64 + lane][jl]);
      pk.z = f2bf(tile[128 + lane][jl]);
      pk.w = f2bf(tile[192 + lane][jl]);
      ((ushort4*)(yT + (size_t)(j0 + jl) * CC))[lane] = pk;
    }
  }
}

// Kernel 2: one wave per o: gather+max over 32 indices, write red[o][c] (f32)
__global__ __launch_bounds__(256) void gather_kernel(
    const ushortT* __restrict__ yT, const int* __restrict__ A, float* __restrict__ red) {
  const int t = threadIdx.x;
  const int lane = t & 63;
  const int wave = t >> 6;
  const int o = blockIdx.x * 4 + wave;

  const int4* A4 = (const int4*)(A + (size_t)o * DD);
  int4 id[8];
  #pragma unroll
  for (int q = 0; q < 8; ++q) id[q] = A4[q];

  float a0 = -INFINITY, a1 = -INFINITY, a2 = -INFINITY, a3 = -INFINITY;
  #pragma unroll
  for (int q = 0; q < 8; ++q) {
    int ids[4] = {id[q].x, id[q].y, id[q].z, id[q].w};
    #pragma unroll
    for (int e = 0; e < 4; ++e) {
      const ushort4 v = ((const ushort4*)(yT + (size_t)ids[e] * CC))[lane];
      a0 = fmaxf(a0, bf2f(v.x));
      a1 = fmaxf(a1, bf2f(v.y));
      a2 = fmaxf(a2, bf2f(v.z));
      a3 = fmaxf(a3, bf2f(v.w));
    }
  }
  // un-permute: ushort slot 4*lane+m held c = 64*m+lane -> 4 coalesced 256B stores
  float* ro = red + (size_t)o * CC + lane;
  ro[0]   = a0;
  ro[64]  = a1;
  ro[128] = a2;
  ro[192] = a3;
}

// Kernel 3: out[n,k,o] = sum_i red[o][n*32+i]*ft[i][k] + bias[k][o]
// block: n-pair (np) x 64-o tile; wave: (n parity, k-half); lane = o_local
__global__ __launch_bounds__(256) void out_kernel(
    const float* __restrict__ red, const float* __restrict__ ft,
    const float* __restrict__ bias, float* __restrict__ out) {
  __shared__ float rtile[64][65];   // [o_local][c_local], pad 65 -> 2-way max on reads
  __shared__ float ftl[32][64];
  const int t = threadIdx.x;
  const int lane = t & 63;
  const int wave = t >> 6;
  const int np = blockIdx.x >> 7;   // 0..3
  const int ot = blockIdx.x & 127;  // 0..127
  const int o0 = ot * 64;
  const int c0 = np * 64;

  // ft -> LDS (2048 floats, coalesced)
  #pragma unroll
  for (int q = 0; q < 8; ++q) {
    const int idx = q * 256 + t;
    ftl[idx >> 6][idx & 63] = ft[idx];
  }
  // red tile -> LDS: per pass a wave loads 4 rows x 256B contiguous
  #pragma unroll
  for (int rr = 0; rr < 4; ++rr) {
    const int row = wave * 16 + rr * 4 + (lane >> 4);
    const int cq = (lane & 15) * 4;
    const float4 v = *(const float4*)(red + (size_t)(o0 + row) * CC + c0 + cq);
    rtile[row][cq + 0] = v.x;
    rtile[row][cq + 1] = v.y;
    rtile[row][cq + 2] = v.z;
    rtile[row][cq + 3] = v.w;
  }
  __syncthreads();

  const int n  = np * 2 + (wave & 1);
  const int kh = (wave >> 1) * 32;
  const int cb = (wave & 1) * 32;

  float rv[32];
  #pragma unroll
  for (int i = 0; i < 32; ++i) rv[i] = rtile[lane][cb + i];   // (lane+cb+i)%32 -> 2-way

  float acc[32];
  #pragma unroll
  for (int kk = 0; kk < 32; ++kk) acc[kk] = 0.f;
  #pragma unroll
  for (int i = 0; i < 32; ++i) {
    #pragma unroll
    for (int kk = 0; kk < 32; ++kk)
      acc[kk] += rv[i] * ftl[i][kh + kk];   // ftl: uniform addr -> broadcast
  }

  float* op = out + (size_t)n * OUTC * OUTN + o0 + lane;
  const float* bp = bias + o0 + lane;
  #pragma unroll
  for (int kk = 0; kk < 32; ++kk) {
    const int k = kh + kk;
    op[(size_t)k * OUTN] = acc[kk] + bp[(size_t)k * OUTN];   // 256B-contiguous stores
  }
}

extern "C" void kernel_launch(void* const* d_in, const int* in_sizes, int n_in,
                              void* d_out, int out_size, void* d_ws, size_t ws_size,
                              hipStream_t stream) {
  const float* x    = (const float*)d_in[0];
  const float* nf   = (const float*)d_in[1];
  const float* ft   = (const float*)d_in[2];
  const float* bias = (const float*)d_in[3];
  const int*   A    = (const int*)d_in[4];
  float* out = (float*)d_out;

  ushortT* yT = (ushortT*)d_ws;                               // 50000*256*2 = 25.6 MB
  float*   red = (float*)((char*)d_ws + (size_t)INN * CC * 2); // 8192*256*4 = 8.4 MB

  hipLaunchKernelGGL(prep_kernel,   dim3((INN + 31) / 32), dim3(256), 0, stream, x, nf, yT);
  hipLaunchKernelGGL(gather_kernel, dim3(OUTN / 4),        dim3(256), 0, stream, yT, A, red);
  hipLaunchKernelGGL(out_kernel,    dim3(512),             dim3(256), 0, stream, red, ft, bias, out);
}

// Round 4
// 51.451 us; speedup vs baseline: 2.0646x; 1.0250x over previous
//
#include <hip/hip_runtime.h>
#include <math.h>

#define NN   8
#define INCH 32
#define INN  50000
#define OUTC 64
#define OUTN 8192
#define DD   32
#define CC   256   // NN*INCH

typedef unsigned short ushortT;

__device__ __forceinline__ ushortT f2bf(float f) {
  unsigned u = __float_as_uint(f);
  unsigned r = (u + 0x7FFFu + ((u >> 16) & 1u)) >> 16;   // round-nearest-even
  return (ushortT)r;
}
__device__ __forceinline__ float bf2f(ushortT b) {
  return __uint_as_float(((unsigned)b) << 16);
}

// Kernel 1: yT[j][p] bf16, permuted layout: ushort position p = 4*l + m  <->  c = 64*m + l
// Reads: 8 lanes per row (128B contiguous per lane-group). LDS tile is bf16 (17.4 KB)
// so 8 blocks/CU fit -> full wave-slot occupancy.
__global__ __launch_bounds__(256) void prep_kernel(
    const float* __restrict__ x, const float* __restrict__ nf, ushortT* __restrict__ yT) {
  __shared__ ushortT tile[CC][34];   // stride 34 ushorts (68B): b32-aligned writes, <=2-way banks
  const int t = threadIdx.x;
  const int j0 = blockIdx.x * 32;
  const int jmax = min(32, INN - j0);   // 50000 = 1562*32 + 16 -> last block 16

  const int q  = t & 7;    // j-quad within window
  const int r0 = t >> 3;   // row within 32-row group

  if (q * 4 < jmax) {
    // nf row = c & 31 = r0 for every pass -> loop-invariant
    const float4 nv = *(const float4*)(nf + (size_t)r0 * INN + j0 + 4 * q);
    #pragma unroll
    for (int p = 0; p < 8; ++p) {
      const int c = (p << 5) + r0;
      const float4 xv = *(const float4*)(x + (size_t)c * INN + j0 + 4 * q);
      const unsigned w0 = ((unsigned)f2bf(xv.y * nv.y) << 16) | (unsigned)f2bf(xv.x * nv.x);
      const unsigned w1 = ((unsigned)f2bf(xv.w * nv.w) << 16) | (unsigned)f2bf(xv.z * nv.z);
      *(unsigned*)&tile[c][4 * q]     = w0;   // byte 68c+8q: 4-aligned, bank (17c+2q)%32
      *(unsigned*)&tile[c][4 * q + 2] = w1;
    }
  }
  __syncthreads();

  // store: one full 512B yT row per wave-instruction (ushort4/lane), permuted pack
  const int lane = t & 63;
  const int wave = t >> 6;
  #pragma unroll
  for (int r = 0; r < 8; ++r) {
    const int jl = wave * 8 + r;
    if (jl < jmax) {
      ushort4 pk;
      pk.x = tile[lane][jl];          // u16 read, lanes l vs l+32 alias only -> 2-way (free)
      pk.y = tile[64 + lane][jl];
      pk.z = tile[128 + lane][jl];
      pk.w = tile[192 + lane][jl];
      ((ushort4*)(yT + (size_t)(j0 + jl) * CC))[lane] = pk;
    }
  }
}

// Kernel 2: one wave per o: gather+max over 32 indices, write red16[o][c] (bf16, unpermuted)
__global__ __launch_bounds__(256) void gather_kernel(
    const ushortT* __restrict__ yT, const int* __restrict__ A, ushortT* __restrict__ red16) {
  const int t = threadIdx.x;
  const int lane = t & 63;
  const int wave = t >> 6;
  const int o = blockIdx.x * 4 + wave;

  const int4* A4 = (const int4*)(A + (size_t)o * DD);
  int4 id[8];
  #pragma unroll
  for (int q = 0; q < 8; ++q) id[q] = A4[q];

  float a0 = -INFINITY, a1 = -INFINITY, a2 = -INFINITY, a3 = -INFINITY;
  #pragma unroll
  for (int q = 0; q < 8; ++q) {
    int ids[4] = {id[q].x, id[q].y, id[q].z, id[q].w};
    #pragma unroll
    for (int e = 0; e < 4; ++e) {
      const ushort4 v = ((const ushort4*)(yT + (size_t)ids[e] * CC))[lane];
      a0 = fmaxf(a0, bf2f(v.x));
      a1 = fmaxf(a1, bf2f(v.y));
      a2 = fmaxf(a2, bf2f(v.z));
      a3 = fmaxf(a3, bf2f(v.w));
    }
  }
  // un-permute: slot 4*lane+m held c = 64*m+lane. f2bf is EXACT here (inputs already bf16).
  // 4 stores, each 64 lanes x 2B contiguous = 128B line.
  ushortT* ro = red16 + (size_t)o * CC + lane;
  ro[0]   = f2bf(a0);
  ro[64]  = f2bf(a1);
  ro[128] = f2bf(a2);
  ro[192] = f2bf(a3);
}

// Kernel 3: out[n,k,o] = sum_i red[o][n*32+i]*ft[i][k] + bias[k][o]
// block: n-pair (np) x 64-o tile; wave: (n parity, k-half); lane = o_local
__global__ __launch_bounds__(256) void out_kernel(
    const ushortT* __restrict__ red16, const float* __restrict__ ft,
    const float* __restrict__ bias, float* __restrict__ out) {
  __shared__ float rtile[64][65];   // [o_local][c_local], pad 65 -> <=2-way on all phases
  __shared__ float ftl[32][64];
  const int t = threadIdx.x;
  const int lane = t & 63;
  const int wave = t >> 6;
  const int np = blockIdx.x >> 7;   // 0..3
  const int ot = blockIdx.x & 127;  // 0..127
  const int o0 = ot * 64;
  const int c0 = np * 64;

  // ft -> LDS (2048 floats, coalesced)
  #pragma unroll
  for (int q = 0; q < 8; ++q) {
    const int idx = q * 256 + t;
    ftl[idx >> 6][idx & 63] = ft[idx];
  }
  // red16 tile -> LDS: thread covers 8 c's (16B) of a row; per wave: 8 rows x 128B contiguous
  #pragma unroll
  for (int i = 0; i < 2; ++i) {
    const int r = (t >> 3) + 32 * i;
    const int g = t & 7;
    const ushort4* src = (const ushort4*)(red16 + (size_t)(o0 + r) * CC + c0 + g * 8);
    const ushort4 v0 = src[0];
    const ushort4 v1 = src[1];
    float* dst = &rtile[r][g * 8];
    dst[0] = bf2f(v0.x); dst[1] = bf2f(v0.y); dst[2] = bf2f(v0.z); dst[3] = bf2f(v0.w);
    dst[4] = bf2f(v1.x); dst[5] = bf2f(v1.y); dst[6] = bf2f(v1.z); dst[7] = bf2f(v1.w);
  }
  __syncthreads();

  const int n  = np * 2 + (wave & 1);
  const int kh = (wave >> 1) * 32;
  const int cb = (wave & 1) * 32;

  float rv[32];
  #pragma unroll
  for (int i = 0; i < 32; ++i) rv[i] = rtile[lane][cb + i];   // (lane+cb+i)%32 -> 2-way

  float acc[32];
  #pragma unroll
  for (int kk = 0; kk < 32; ++kk) acc[kk] = 0.f;
  #pragma unroll
  for (int i = 0; i < 32; ++i) {
    #pragma unroll
    for (int kk = 0; kk < 32; ++kk)
      acc[kk] += rv[i] * ftl[i][kh + kk];   // ftl: uniform addr -> broadcast
  }

  float* op = out + (size_t)n * OUTC * OUTN + o0 + lane;
  const float* bp = bias + o0 + lane;
  #pragma unroll
  for (int kk = 0; kk < 32; ++kk) {
    const int k = kh + kk;
    op[(size_t)k * OUTN] = acc[kk] + bp[(size_t)k * OUTN];   // 256B-contiguous stores
  }
}

extern "C" void kernel_launch(void* const* d_in, const int* in_sizes, int n_in,
                              void* d_out, int out_size, void* d_ws, size_t ws_size,
                              hipStream_t stream) {
  const float* x    = (const float*)d_in[0];
  const float* nf   = (const float*)d_in[1];
  const float* ft   = (const float*)d_in[2];
  const float* bias = (const float*)d_in[3];
  const int*   A    = (const int*)d_in[4];
  float* out = (float*)d_out;

  ushortT* yT    = (ushortT*)d_ws;                                // 50000*256*2 = 25.6 MB
  ushortT* red16 = (ushortT*)((char*)d_ws + (size_t)INN * CC * 2); // 8192*256*2 = 4.2 MB

  hipLaunchKernelGGL(prep_kernel,   dim3((INN + 31) / 32), dim3(256), 0, stream, x, nf, yT);
  hipLaunchKernelGGL(gather_kernel, dim3(OUTN / 4),        dim3(256), 0, stream, yT, A, red16);
  hipLaunchKernelGGL(out_kernel,    dim3(512),             dim3(256), 0, stream, red16, ft, bias, out);
}